// Round 10
// baseline (435.532 us; speedup 1.0000x reference)
//
#include <hip/hip_runtime.h>
#include <hip/hip_cooperative_groups.h>
#include <math.h>

namespace cg = cooperative_groups;

#define B_ 8
#define N_ 2000
#define H_ 128
#define K_ 32
#define M_ (B_*N_)     // 16000
#define KTOT 384       // [in_agg(128) | out_agg(128) | h(128)]
#define NC 512         // cols j = d*4 + g
#define NTILES 32      // NC/16
#define NCHUNK 12      // KTOT/32
#define AGG_BLOCKS (M_ / 8)           // 2000
#define PREP_BLOCKS (NTILES * NCHUNK) // 384
#define GRID_ 512                     // 64 per XCD; 2/CU guaranteed resident

typedef __attribute__((ext_vector_type(8))) short s8_t;
typedef __attribute__((ext_vector_type(4))) float f4_t;

__device__ __forceinline__ unsigned short f2bf(float x) {
    union { float f; unsigned u; } v; v.f = x;
    unsigned r = v.u + 0x7fff + ((v.u >> 16) & 1);   // RN-even
    return (unsigned short)(r >> 16);
}
__device__ __forceinline__ float bf2f(unsigned short b) {
    union { unsigned u; float f; } v; v.u = (unsigned)b << 16; return v.f;
}
__device__ __forceinline__ float sigm_(float x) { return 1.f / (1.f + __expf(-x)); }
__device__ __forceinline__ float tanh_(float x) { return 2.f / (1.f + __expf(-2.f * x)) - 1.f; }

__device__ __forceinline__ float pickv(f4_t A, int m) {
    float ab = (m & 1) ? A.y : A.x;
    float cd = (m & 1) ? A.w : A.z;
    return (m & 2) ? cd : ab;
}
__device__ __forceinline__ float pick4(float u0, float u1, float u2, float u3, int m) {
    float ab = (m & 1) ? u1 : u0;
    float cd = (m & 1) ? u3 : u2;
    return (m & 2) ? cd : ab;
}

__device__ __forceinline__ void split4(const float* f, ushort4& hi, ushort4& lo) {
    unsigned short h0 = f2bf(f[0]), h1 = f2bf(f[1]), h2 = f2bf(f[2]), h3 = f2bf(f[3]);
    hi = make_ushort4(h0, h1, h2, h3);
    lo = make_ushort4(f2bf(f[0] - bf2f(h0)), f2bf(f[1] - bf2f(h1)),
                      f2bf(f[2] - bf2f(h2)), f2bf(f[3] - bf2f(h3)));
}

// async global->LDS, 16 B per lane; LDS dest = wave-uniform base + lane*16
__device__ __forceinline__ void gload_lds(const unsigned short* g, short* l) {
    __builtin_amdgcn_global_load_lds(
        (const __attribute__((address_space(1))) unsigned*)g,
        (__attribute__((address_space(3))) unsigned*)l, 16, 0, 0);
}

// W prep: element t (0..511) of prep-block pb = (ntile*NCHUNK + chunk).
__device__ __forceinline__ void prep_elem(int pb, int t,
                                          const float* __restrict__ w_in,
                                          const float* __restrict__ w_out,
                                          const float* __restrict__ u_in,
                                          const float* __restrict__ u_out,
                                          unsigned short* __restrict__ wp_hi,
                                          unsigned short* __restrict__ wp_lo) {
    int ntile = pb / NCHUNK, chunk = pb % NCHUNK;
    int lane = t >> 3, e = t & 7;
    int col = ntile * 16 + (lane & 15);
    int k = chunk * 32 + (lane >> 4) * 8 + e;
    int d = col >> 2, g = col & 3;
    float v;
    if (k < 128) {
        v = w_in[(g * 128 + k) * 128 + d];
    } else if (k < 256) {
        v = w_out[(g * 128 + (k - 128)) * 128 + d];
    } else {
        int kk = k - 256;
        v = u_in[(g * 128 + kk) * 128 + d] + u_out[(g * 128 + kk) * 128 + d];
    }
    unsigned short hs = f2bf(v);
    wp_hi[(size_t)pb * 512 + t] = hs;
    wp_lo[(size_t)pb * 512 + t] = f2bf(v - bf2f(hs));
}

// Gather + masked aggregate + u-term pack for agg-unit a (rows 8a..8a+7);
// output split-bf16 in MFMA A-fragment layout (verified R4-R8).
__device__ __forceinline__ void agg_body(int a, int tid,
                                         const float* __restrict__ h,
                                         const int* __restrict__ in_idx,
                                         const float* __restrict__ in_mask,
                                         const int* __restrict__ out_idx,
                                         const float* __restrict__ out_mask,
                                         unsigned short* __restrict__ A_hi,
                                         unsigned short* __restrict__ A_lo,
                                         int (*s_idx)[64], float (*s_msk)[64]) {
    int r = tid >> 5;            // 0..7 row within unit
    int p = tid & 31;            // dim group: dims p*4 .. p*4+3
    int row = a * 8 + r;
    int b = row / N_;
    const float* hb = h + (size_t)b * N_ * H_;

    for (int e = tid; e < 512; e += 256) {
        int r2 = e >> 6, q = e & 63;
        int ridx = a * 8 + r2;
        if (q < 32) {
            s_idx[r2][q] = in_idx[ridx * K_ + q];
            s_msk[r2][q] = in_mask[ridx * K_ + q];
        } else {
            s_idx[r2][q] = out_idx[ridx * K_ + (q - 32)];
            s_msk[r2][q] = out_mask[ridx * K_ + (q - 32)];
        }
    }
    __syncthreads();

    int d0 = p * 4;
    float ai[4] = {0.f, 0.f, 0.f, 0.f};
    float ao[4] = {0.f, 0.f, 0.f, 0.f};
    #pragma unroll 16
    for (int k = 0; k < K_; ++k) {
        int   i1 = s_idx[r][k];
        float m1 = s_msk[r][k];
        int   i2 = s_idx[r][32 + k];
        float m2 = s_msk[r][32 + k];
        float4 v1 = *(const float4*)(hb + (size_t)i1 * H_ + d0);
        float4 v2 = *(const float4*)(hb + (size_t)i2 * H_ + d0);
        ai[0] += m1 * v1.x; ai[1] += m1 * v1.y; ai[2] += m1 * v1.z; ai[3] += m1 * v1.w;
        ao[0] += m2 * v2.x; ao[1] += m2 * v2.y; ao[2] += m2 * v2.z; ao[3] += m2 * v2.w;
    }
    float4 hv4 = *(const float4*)(h + (size_t)row * H_ + d0);
    float hh[4] = {hv4.x, hv4.y, hv4.z, hv4.w};

    int mtile = row >> 4;
    int kg = (p >> 1) & 3;
    int e0 = (p & 1) * 4;
    int lane = (row & 15) + 16 * kg;
    size_t bi = ((size_t)(mtile * NCHUNK +     (p >> 3)) * 64 + lane) * 8 + e0;
    size_t bo = ((size_t)(mtile * NCHUNK + 4 + (p >> 3)) * 64 + lane) * 8 + e0;
    size_t bh = ((size_t)(mtile * NCHUNK + 8 + (p >> 3)) * 64 + lane) * 8 + e0;

    ushort4 hi, lo;
    split4(ai, hi, lo); *(ushort4*)(A_hi + bi) = hi; *(ushort4*)(A_lo + bi) = lo;
    split4(ao, hi, lo); *(ushort4*)(A_hi + bo) = hi; *(ushort4*)(A_lo + bo) = lo;
    split4(hh, hi, lo); *(ushort4*)(A_hi + bh) = hi; *(ushort4*)(A_lo + bh) = lo;
}

// R6 gemm body (best measured): 128x128 tile, 4 waves, wave tile 64x64;
// per chunk 32 KB staged via global_load_lds, 2-barrier K-loop, fused gates.
__device__ __forceinline__ void gemm_body(int mt, int jt, int tid, short* sL,
                const unsigned short* __restrict__ A_hi,
                const unsigned short* __restrict__ A_lo,
                const unsigned short* __restrict__ wp_hi,
                const unsigned short* __restrict__ wp_lo,
                const float* __restrict__ bias,
                const float* __restrict__ c_src,
                float* __restrict__ c_dst,
                float* __restrict__ h_dst,
                int write_c) {
    int lane = tid & 63;
    int w    = tid >> 6;         // 0..3
    int wm   = w & 1;
    int wn   = w >> 1;
    int mtile0 = mt * 8;
    int ntile0 = jt * 8;

    const unsigned short* gp[8];
    short* lp[8];
    #pragma unroll
    for (int i = 0; i < 8; ++i) {
        int s = i * 4 + w;
        const unsigned short* src;
        if (s < 8)       src = A_hi  + ((size_t)((mtile0 + s)      * NCHUNK) * 64 + lane) * 8;
        else if (s < 16) src = A_lo  + ((size_t)((mtile0 + s - 8)  * NCHUNK) * 64 + lane) * 8;
        else if (s < 24) src = wp_hi + ((size_t)((ntile0 + s - 16) * NCHUNK) * 64 + lane) * 8;
        else             src = wp_lo + ((size_t)((ntile0 + s - 24) * NCHUNK) * 64 + lane) * 8;
        gp[i] = src;
        lp[i] = &sL[s * 512];    // wave-uniform base; HW adds lane*16 B
    }

    f4_t zero = {0.f, 0.f, 0.f, 0.f};
    f4_t acc[4][4];
    #pragma unroll
    for (int i = 0; i < 4; ++i)
        #pragma unroll
        for (int j = 0; j < 4; ++j) acc[i][j] = zero;

    #pragma unroll 1
    for (int c = 0; c < NCHUNK; ++c) {
        __syncthreads();
        #pragma unroll
        for (int i = 0; i < 8; ++i) {
            gload_lds(gp[i], lp[i]);
            gp[i] += 512;
        }
        __syncthreads();

        s8_t a_hi[4], a_lo[4], b_hi[4], b_lo[4];
        #pragma unroll
        for (int i = 0; i < 4; ++i) {
            a_hi[i] = *(const s8_t*)&sL[(wm * 4 + i) * 512 + lane * 8];
            a_lo[i] = *(const s8_t*)&sL[(8 + wm * 4 + i) * 512 + lane * 8];
        }
        #pragma unroll
        for (int j = 0; j < 4; ++j) {
            b_hi[j] = *(const s8_t*)&sL[(16 + wn * 4 + j) * 512 + lane * 8];
            b_lo[j] = *(const s8_t*)&sL[(24 + wn * 4 + j) * 512 + lane * 8];
        }
        #pragma unroll
        for (int i = 0; i < 4; ++i)
            #pragma unroll
            for (int j = 0; j < 4; ++j) {
                acc[i][j] = __builtin_amdgcn_mfma_f32_16x16x32_bf16(a_hi[i], b_hi[j], acc[i][j], 0, 0, 0);
                acc[i][j] = __builtin_amdgcn_mfma_f32_16x16x32_bf16(a_hi[i], b_lo[j], acc[i][j], 0, 0, 0);
                acc[i][j] = __builtin_amdgcn_mfma_f32_16x16x32_bf16(a_lo[i], b_hi[j], acc[i][j], 0, 0, 0);
            }
    }

    int g    = lane & 3;
    int qrow = lane >> 4;
    int dl   = (lane >> 2) & 3;
    #pragma unroll
    for (int j = 0; j < 4; ++j) {
        int ncol_base = jt * 128 + wn * 64 + j * 16;
        int d = (ncol_base >> 2) + dl;
        float b0 = bias[0 * 128 + d];
        float b1 = bias[1 * 128 + d];
        float b2 = bias[2 * 128 + d];
        float b3 = bias[3 * 128 + d];
        #pragma unroll
        for (int i = 0; i < 4; ++i) {
            f4_t A = acc[i][j];
            float s0 = pickv(A, g);
            float s1 = pickv(A, g ^ 1);
            float s2 = pickv(A, g ^ 2);
            float s3 = pickv(A, g ^ 3);
            float u0 = s0;
            float u1 = __shfl_xor(s1, 1);
            float u2 = __shfl_xor(s2, 2);
            float u3 = __shfl_xor(s3, 3);
            float p0 = pick4(u0, u1, u2, u3, g) + b0;
            float p1 = pick4(u0, u1, u2, u3, g ^ 1) + b1;
            float p2 = pick4(u0, u1, u2, u3, g ^ 2) + b2;
            float p3 = pick4(u0, u1, u2, u3, g ^ 3) + b3;
            float ig = sigm_(p0);
            float og = sigm_(p1);
            float fg = sigm_(p2);
            float cg = tanh_(p3);
            int row = mt * 128 + wm * 64 + i * 16 + qrow * 4 + g;
            size_t off = (size_t)row * H_ + d;
            float c_old = c_src[off];
            float c_new = fg * c_old + ig * cg;
            if (write_c) c_dst[off] = c_new;
            h_dst[off] = og * tanh_(c_new);
        }
    }
}

// ---------------- cooperative persistent kernel ----------------
__global__ __launch_bounds__(256, 2)
void fused_all(const float* __restrict__ node_hidden,
               const float* __restrict__ cell,
               const float* __restrict__ w_in,
               const float* __restrict__ w_out,
               const float* __restrict__ u_in,
               const float* __restrict__ u_out,
               const float* __restrict__ bias,
               const float* __restrict__ in_mask,
               const float* __restrict__ out_mask,
               const int* __restrict__ in_idx,
               const int* __restrict__ out_idx,
               unsigned short* __restrict__ wp_hi,
               unsigned short* __restrict__ wp_lo,
               unsigned short* __restrict__ A_hi,
               unsigned short* __restrict__ A_lo,
               float* __restrict__ h_buf,
               float* __restrict__ out) {
    __shared__ short sL[32 * 512];   // 32 KB; agg phase aliases first 4 KB
    cg::grid_group grid = cg::this_grid();
    int tid = threadIdx.x;
    int pb  = blockIdx.x;
    int x   = pb & 7;       // XCD
    int sl  = pb >> 3;      // 0..63 slot within XCD

    int (*s_idx)[64] = (int(*)[64])sL;                 // 2 KB
    float (*s_msk)[64] = (float(*)[64])(sL + 1024);    // next 2 KB

    // gemm tile mapping (fixed for both layers); per-XCD tile count <= 64
    int glo = (125 * x + 7) >> 3;
    int ghi = (125 * (x + 1) + 7) >> 3;
    int gcnt = (ghi - glo) * 4;
    int gmt = glo + (sl >> 2);
    int gjt = sl & 3;

    // ---- phase A: W prep + layer-0 agg ----
    if (pb < PREP_BLOCKS) {
        prep_elem(pb, tid,       w_in, w_out, u_in, u_out, wp_hi, wp_lo);
        prep_elem(pb, tid + 256, w_in, w_out, u_in, u_out, wp_hi, wp_lo);
    }
    for (int q = sl; q < 250; q += 64) {
        agg_body(x * 250 + q, tid, node_hidden, in_idx, in_mask,
                 out_idx, out_mask, A_hi, A_lo, s_idx, s_msk);
        __syncthreads();
    }
    grid.sync();

    // ---- phase B: layer-0 gemm (c -> out, h -> h_buf) ----
    if (sl < gcnt)
        gemm_body(gmt, gjt, tid, sL, A_hi, A_lo, wp_hi, wp_lo, bias,
                  cell, out, h_buf, 1);
    grid.sync();

    // ---- phase C: layer-1 agg ----
    for (int q = sl; q < 250; q += 64) {
        agg_body(x * 250 + q, tid, h_buf, in_idx, in_mask,
                 out_idx, out_mask, A_hi, A_lo, s_idx, s_msk);
        __syncthreads();
    }
    grid.sync();

    // ---- phase D: layer-1 gemm (c from out, final h -> out) ----
    if (sl < gcnt)
        gemm_body(gmt, gjt, tid, sL, A_hi, A_lo, wp_hi, wp_lo, bias,
                  out, out, out, 0);
}

// ---------------- fallback standalone kernels (R8, proven) ----------------
__global__ __launch_bounds__(256)
void agg0_prep_kernel(const float* __restrict__ h,
                      const int* __restrict__ in_idx,
                      const float* __restrict__ in_mask,
                      const int* __restrict__ out_idx,
                      const float* __restrict__ out_mask,
                      unsigned short* __restrict__ A_hi,
                      unsigned short* __restrict__ A_lo,
                      const float* __restrict__ w_in,
                      const float* __restrict__ w_out,
                      const float* __restrict__ u_in,
                      const float* __restrict__ u_out,
                      unsigned short* __restrict__ wp_hi,
                      unsigned short* __restrict__ wp_lo) {
    __shared__ int   s_idx[8][64];
    __shared__ float s_msk[8][64];
    int tid = threadIdx.x;
    if (blockIdx.x < AGG_BLOCKS) {
        int bid = (blockIdx.x & 7) * 250 + (blockIdx.x >> 3);
        agg_body(bid, tid, h, in_idx, in_mask, out_idx, out_mask,
                 A_hi, A_lo, s_idx, s_msk);
    } else {
        int pb = blockIdx.x - AGG_BLOCKS;
        prep_elem(pb, tid,       w_in, w_out, u_in, u_out, wp_hi, wp_lo);
        prep_elem(pb, tid + 256, w_in, w_out, u_in, u_out, wp_hi, wp_lo);
    }
}

__global__ __launch_bounds__(256)
void agg_kernel(const float* __restrict__ h,
                const int* __restrict__ in_idx,
                const float* __restrict__ in_mask,
                const int* __restrict__ out_idx,
                const float* __restrict__ out_mask,
                unsigned short* __restrict__ A_hi,
                unsigned short* __restrict__ A_lo) {
    __shared__ int   s_idx[8][64];
    __shared__ float s_msk[8][64];
    int bid = (blockIdx.x & 7) * 250 + (blockIdx.x >> 3);
    agg_body(bid, threadIdx.x, h, in_idx, in_mask, out_idx, out_mask,
             A_hi, A_lo, s_idx, s_msk);
}

__global__ __launch_bounds__(256)
void gemm_gates(const unsigned short* __restrict__ A_hi,
                const unsigned short* __restrict__ A_lo,
                const unsigned short* __restrict__ wp_hi,
                const unsigned short* __restrict__ wp_lo,
                const float* __restrict__ bias,
                const float* __restrict__ c_src,
                float* __restrict__ c_dst,
                float* __restrict__ h_dst,
                int write_c) {
    __shared__ short sL[32 * 512];
    gemm_body(blockIdx.x, blockIdx.y, threadIdx.x, sL,
              A_hi, A_lo, wp_hi, wp_lo, bias, c_src, c_dst, h_dst, write_c);
}

extern "C" void kernel_launch(void* const* d_in, const int* in_sizes, int n_in,
                              void* d_out, int out_size, void* d_ws, size_t ws_size,
                              hipStream_t stream) {
    const float* node_hidden = (const float*)d_in[0];
    const float* cell        = (const float*)d_in[1];
    const float* w_in        = (const float*)d_in[2];
    const float* w_out       = (const float*)d_in[3];
    const float* u_in        = (const float*)d_in[4];
    const float* u_out       = (const float*)d_in[5];
    const float* bias        = (const float*)d_in[6];
    const float* in_mask     = (const float*)d_in[7];
    const float* out_mask    = (const float*)d_in[8];
    const int*   in_idx      = (const int*)d_in[9];
    const int*   out_idx     = (const int*)d_in[10];
    float* out = (float*)d_out;

    char* p = (char*)d_ws;
    unsigned short* wp_hi = (unsigned short*)p; p += (size_t)NTILES * NCHUNK * 512 * 2;      // 384 KB
    unsigned short* wp_lo = (unsigned short*)p; p += (size_t)NTILES * NCHUNK * 512 * 2;
    unsigned short* A_hi  = (unsigned short*)p; p += (size_t)(M_/16) * NCHUNK * 512 * 2;     // 12 MB
    unsigned short* A_lo  = (unsigned short*)p; p += (size_t)(M_/16) * NCHUNK * 512 * 2;
    float* h_buf = (float*)p;                   p += (size_t)M_ * H_ * 4;                    // 8 MB

    void* args[] = {
        (void*)&node_hidden, (void*)&cell, (void*)&w_in, (void*)&w_out,
        (void*)&u_in, (void*)&u_out, (void*)&bias, (void*)&in_mask,
        (void*)&out_mask, (void*)&in_idx, (void*)&out_idx,
        (void*)&wp_hi, (void*)&wp_lo, (void*)&A_hi, (void*)&A_lo,
        (void*)&h_buf, (void*)&out
    };
    hipError_t err = hipLaunchCooperativeKernel((const void*)fused_all,
                                                dim3(GRID_), dim3(256),
                                                args, 0, stream);
    if (err != hipSuccess) {
        // deterministic fallback: proven R8 4-dispatch path (same buffers)
        agg0_prep_kernel<<<AGG_BLOCKS + PREP_BLOCKS, 256, 0, stream>>>(
            node_hidden, in_idx, in_mask, out_idx, out_mask, A_hi, A_lo,
            w_in, w_out, u_in, u_out, wp_hi, wp_lo);
        gemm_gates<<<dim3(M_ / 128, 4), 256, 0, stream>>>(
            A_hi, A_lo, wp_hi, wp_lo, bias, cell, out, h_buf, 1);
        agg_kernel<<<AGG_BLOCKS, 256, 0, stream>>>(h_buf, in_idx, in_mask,
                                                   out_idx, out_mask, A_hi, A_lo);
        gemm_gates<<<dim3(M_ / 128, 4), 256, 0, stream>>>(
            A_hi, A_lo, wp_hi, wp_lo, bias, out, out, out, 0);
    }
}

// Round 11
// 189.148 us; speedup vs baseline: 2.3026x; 2.3026x over previous
//
#include <hip/hip_runtime.h>
#include <math.h>

#define B_ 8
#define N_ 2000
#define H_ 128
#define K_ 32
#define M_ (B_*N_)     // 16000
#define KTOT 384       // [in_agg(128) | out_agg(128) | h(128)]
#define NC 512         // cols j = d*4 + g
#define NTILES 32      // NC/16
#define NCHUNK 12      // KTOT/32
#define AGG_BLOCKS (M_ / 8)           // 2000
#define PREP_BLOCKS (NTILES * NCHUNK) // 384
#define GEMM_BLOCKS 512               // 8 XCDs x <=64 tile-slots

typedef __attribute__((ext_vector_type(8))) short s8_t;
typedef __attribute__((ext_vector_type(4))) float f4_t;

__device__ __forceinline__ unsigned short f2bf(float x) {
    union { float f; unsigned u; } v; v.f = x;
    unsigned r = v.u + 0x7fff + ((v.u >> 16) & 1);   // RN-even
    return (unsigned short)(r >> 16);
}
__device__ __forceinline__ float bf2f(unsigned short b) {
    union { unsigned u; float f; } v; v.u = (unsigned)b << 16; return v.f;
}
__device__ __forceinline__ float sigm_(float x) { return 1.f / (1.f + __expf(-x)); }
__device__ __forceinline__ float tanh_(float x) { return 2.f / (1.f + __expf(-2.f * x)) - 1.f; }

__device__ __forceinline__ float pickv(f4_t A, int m) {
    float ab = (m & 1) ? A.y : A.x;
    float cd = (m & 1) ? A.w : A.z;
    return (m & 2) ? cd : ab;
}
__device__ __forceinline__ float pick4(float u0, float u1, float u2, float u3, int m) {
    float ab = (m & 1) ? u1 : u0;
    float cd = (m & 1) ? u3 : u2;
    return (m & 2) ? cd : ab;
}

__device__ __forceinline__ void split4(const float* f, ushort4& hi, ushort4& lo) {
    unsigned short h0 = f2bf(f[0]), h1 = f2bf(f[1]), h2 = f2bf(f[2]), h3 = f2bf(f[3]);
    hi = make_ushort4(h0, h1, h2, h3);
    lo = make_ushort4(f2bf(f[0] - bf2f(h0)), f2bf(f[1] - bf2f(h1)),
                      f2bf(f[2] - bf2f(h2)), f2bf(f[3] - bf2f(h3)));
}

// async global->LDS, 16 B per lane; LDS dest = wave-uniform base + lane*16
__device__ __forceinline__ void gload_lds(const unsigned short* g, short* l) {
    __builtin_amdgcn_global_load_lds(
        (const __attribute__((address_space(1))) unsigned*)g,
        (__attribute__((address_space(3))) unsigned*)l, 16, 0, 0);
}

// W prep: element t (0..511) of prep-block pb = (ntile*NCHUNK + chunk).
__device__ __forceinline__ void prep_elem(int pb, int t,
                                          const float* __restrict__ w_in,
                                          const float* __restrict__ w_out,
                                          const float* __restrict__ u_in,
                                          const float* __restrict__ u_out,
                                          unsigned short* __restrict__ wp_hi,
                                          unsigned short* __restrict__ wp_lo) {
    int ntile = pb / NCHUNK, chunk = pb % NCHUNK;
    int lane = t >> 3, e = t & 7;
    int col = ntile * 16 + (lane & 15);
    int k = chunk * 32 + (lane >> 4) * 8 + e;
    int d = col >> 2, g = col & 3;
    float v;
    if (k < 128) {
        v = w_in[(g * 128 + k) * 128 + d];
    } else if (k < 256) {
        v = w_out[(g * 128 + (k - 128)) * 128 + d];
    } else {
        int kk = k - 256;
        v = u_in[(g * 128 + kk) * 128 + d] + u_out[(g * 128 + kk) * 128 + d];
    }
    unsigned short hs = f2bf(v);
    wp_hi[(size_t)pb * 512 + t] = hs;
    wp_lo[(size_t)pb * 512 + t] = f2bf(v - bf2f(hs));
}

// Gather + masked aggregate + u-term pack for agg-unit a (rows 8a..8a+7);
// output split-bf16 in MFMA A-fragment layout (verified R4-R10).
__device__ __forceinline__ void agg_body(int a, int tid,
                                         const float* __restrict__ h,
                                         const int* __restrict__ in_idx,
                                         const float* __restrict__ in_mask,
                                         const int* __restrict__ out_idx,
                                         const float* __restrict__ out_mask,
                                         unsigned short* __restrict__ A_hi,
                                         unsigned short* __restrict__ A_lo,
                                         int (*s_idx)[64], float (*s_msk)[64]) {
    int r = tid >> 5;            // 0..7 row within unit
    int p = tid & 31;            // dim group: dims p*4 .. p*4+3
    int row = a * 8 + r;
    int b = row / N_;
    const float* hb = h + (size_t)b * N_ * H_;

    for (int e = tid; e < 512; e += 256) {
        int r2 = e >> 6, q = e & 63;
        int ridx = a * 8 + r2;
        if (q < 32) {
            s_idx[r2][q] = in_idx[ridx * K_ + q];
            s_msk[r2][q] = in_mask[ridx * K_ + q];
        } else {
            s_idx[r2][q] = out_idx[ridx * K_ + (q - 32)];
            s_msk[r2][q] = out_mask[ridx * K_ + (q - 32)];
        }
    }
    __syncthreads();

    int d0 = p * 4;
    float ai[4] = {0.f, 0.f, 0.f, 0.f};
    float ao[4] = {0.f, 0.f, 0.f, 0.f};
    #pragma unroll 16
    for (int k = 0; k < K_; ++k) {
        int   i1 = s_idx[r][k];
        float m1 = s_msk[r][k];
        int   i2 = s_idx[r][32 + k];
        float m2 = s_msk[r][32 + k];
        float4 v1 = *(const float4*)(hb + (size_t)i1 * H_ + d0);
        float4 v2 = *(const float4*)(hb + (size_t)i2 * H_ + d0);
        ai[0] += m1 * v1.x; ai[1] += m1 * v1.y; ai[2] += m1 * v1.z; ai[3] += m1 * v1.w;
        ao[0] += m2 * v2.x; ao[1] += m2 * v2.y; ao[2] += m2 * v2.z; ao[3] += m2 * v2.w;
    }
    float4 hv4 = *(const float4*)(h + (size_t)row * H_ + d0);
    float hh[4] = {hv4.x, hv4.y, hv4.z, hv4.w};

    int mtile = row >> 4;
    int kg = (p >> 1) & 3;
    int e0 = (p & 1) * 4;
    int lane = (row & 15) + 16 * kg;
    size_t bi = ((size_t)(mtile * NCHUNK +     (p >> 3)) * 64 + lane) * 8 + e0;
    size_t bo = ((size_t)(mtile * NCHUNK + 4 + (p >> 3)) * 64 + lane) * 8 + e0;
    size_t bh = ((size_t)(mtile * NCHUNK + 8 + (p >> 3)) * 64 + lane) * 8 + e0;

    ushort4 hi, lo;
    split4(ai, hi, lo); *(ushort4*)(A_hi + bi) = hi; *(ushort4*)(A_lo + bi) = lo;
    split4(ao, hi, lo); *(ushort4*)(A_hi + bo) = hi; *(ushort4*)(A_lo + bo) = lo;
    split4(hh, hi, lo); *(ushort4*)(A_hi + bh) = hi; *(ushort4*)(A_lo + bh) = lo;
}

// Layer-0 combined dispatch: blocks [0,2000) = agg on node_hidden,
// blocks [2000, 2384) = W prep.
__global__ __launch_bounds__(256)
void agg0_prep_kernel(const float* __restrict__ h,
                      const int* __restrict__ in_idx,
                      const float* __restrict__ in_mask,
                      const int* __restrict__ out_idx,
                      const float* __restrict__ out_mask,
                      unsigned short* __restrict__ A_hi,
                      unsigned short* __restrict__ A_lo,
                      const float* __restrict__ w_in,
                      const float* __restrict__ w_out,
                      const float* __restrict__ u_in,
                      const float* __restrict__ u_out,
                      unsigned short* __restrict__ wp_hi,
                      unsigned short* __restrict__ wp_lo) {
    __shared__ int   s_idx[8][64];
    __shared__ float s_msk[8][64];
    int tid = threadIdx.x;
    if (blockIdx.x < AGG_BLOCKS) {
        int bid = (blockIdx.x & 7) * 250 + (blockIdx.x >> 3);  // XCD-affinity swizzle
        agg_body(bid, tid, h, in_idx, in_mask, out_idx, out_mask,
                 A_hi, A_lo, s_idx, s_msk);
    } else {
        int pb = blockIdx.x - AGG_BLOCKS;
        prep_elem(pb, tid,       w_in, w_out, u_in, u_out, wp_hi, wp_lo);
        prep_elem(pb, tid + 256, w_in, w_out, u_in, u_out, wp_hi, wp_lo);
    }
}

// Layer-1 agg (h = h_buf)
__global__ __launch_bounds__(256)
void agg_kernel(const float* __restrict__ h,
                const int* __restrict__ in_idx,
                const float* __restrict__ in_mask,
                const int* __restrict__ out_idx,
                const float* __restrict__ out_mask,
                unsigned short* __restrict__ A_hi,
                unsigned short* __restrict__ A_lo) {
    __shared__ int   s_idx[8][64];
    __shared__ float s_msk[8][64];
    int bid = (blockIdx.x & 7) * 250 + (blockIdx.x >> 3);
    agg_body(bid, threadIdx.x, h, in_idx, in_mask, out_idx, out_mask,
             A_hi, A_lo, s_idx, s_msk);
}

// R6/R8 gemm with XCD-affine tile mapping: linear block l, x = l&7 (XCD via
// round-robin dispatch), s = l>>3. Tiles whose A-rows belong to batch x run
// on XCD x, where agg's swizzle wrote them -> A reads are local-L2 hits
// (per-XCD A slice = 3 MB < 4 MB L2). mt range per XCD: mt_lo=(2000x+63)>>7.
__global__ __launch_bounds__(256)
void gemm_gates(const unsigned short* __restrict__ A_hi,
                const unsigned short* __restrict__ A_lo,
                const unsigned short* __restrict__ wp_hi,
                const unsigned short* __restrict__ wp_lo,
                const float* __restrict__ bias,
                const float* __restrict__ c_src,
                float* __restrict__ c_dst,
                float* __restrict__ h_dst,
                int write_c) {
    __shared__ short sL[32 * 512];   // 32 KB: slots 0..7 A_hi, 8..15 A_lo,
                                     // 16..23 W_hi, 24..31 W_lo
    int l = blockIdx.x;
    int x = l & 7;
    int s_slot = l >> 3;
    int mt_lo  = x ? ((2000 * x + 63) >> 7) : 0;
    int mt_nxt = (2000 * (x + 1) + 63) >> 7;         // x=7 -> 125
    int cnt = (mt_nxt - mt_lo) * 4;                  // 60 or 64
    if (s_slot >= cnt) return;
    int mt = mt_lo + (s_slot >> 2);                  // 0..124
    int jt = s_slot & 3;                             // 0..3

    int tid  = threadIdx.x;
    int lane = tid & 63;
    int w    = tid >> 6;         // 0..3
    int wm   = w & 1;
    int wn   = w >> 1;
    int mtile0 = mt * 8;
    int ntile0 = jt * 8;

    const unsigned short* gp[8];
    short* lp[8];
    #pragma unroll
    for (int i = 0; i < 8; ++i) {
        int s = i * 4 + w;
        const unsigned short* src;
        if (s < 8)       src = A_hi  + ((size_t)((mtile0 + s)      * NCHUNK) * 64 + lane) * 8;
        else if (s < 16) src = A_lo  + ((size_t)((mtile0 + s - 8)  * NCHUNK) * 64 + lane) * 8;
        else if (s < 24) src = wp_hi + ((size_t)((ntile0 + s - 16) * NCHUNK) * 64 + lane) * 8;
        else             src = wp_lo + ((size_t)((ntile0 + s - 24) * NCHUNK) * 64 + lane) * 8;
        gp[i] = src;
        lp[i] = &sL[s * 512];    // wave-uniform base; HW adds lane*16 B
    }

    f4_t zero = {0.f, 0.f, 0.f, 0.f};
    f4_t acc[4][4];
    #pragma unroll
    for (int i = 0; i < 4; ++i)
        #pragma unroll
        for (int j = 0; j < 4; ++j) acc[i][j] = zero;

    #pragma unroll 1
    for (int c = 0; c < NCHUNK; ++c) {
        if (c > 0) __syncthreads();
        #pragma unroll
        for (int i = 0; i < 8; ++i) {
            gload_lds(gp[i], lp[i]);
            gp[i] += 512;
        }
        __syncthreads();

        s8_t a_hi[4], a_lo[4], b_hi[4], b_lo[4];
        #pragma unroll
        for (int i = 0; i < 4; ++i) {
            a_hi[i] = *(const s8_t*)&sL[(wm * 4 + i) * 512 + lane * 8];
            a_lo[i] = *(const s8_t*)&sL[(8 + wm * 4 + i) * 512 + lane * 8];
        }
        #pragma unroll
        for (int j = 0; j < 4; ++j) {
            b_hi[j] = *(const s8_t*)&sL[(16 + wn * 4 + j) * 512 + lane * 8];
            b_lo[j] = *(const s8_t*)&sL[(24 + wn * 4 + j) * 512 + lane * 8];
        }
        #pragma unroll
        for (int i = 0; i < 4; ++i)
            #pragma unroll
            for (int j = 0; j < 4; ++j) {
                acc[i][j] = __builtin_amdgcn_mfma_f32_16x16x32_bf16(a_hi[i], b_hi[j], acc[i][j], 0, 0, 0);
                acc[i][j] = __builtin_amdgcn_mfma_f32_16x16x32_bf16(a_hi[i], b_lo[j], acc[i][j], 0, 0, 0);
                acc[i][j] = __builtin_amdgcn_mfma_f32_16x16x32_bf16(a_lo[i], b_hi[j], acc[i][j], 0, 0, 0);
            }
    }

    // ---- epilogue: gate exchange + cell/h update (verified R2-R10) ----
    int g    = lane & 3;
    int qrow = lane >> 4;
    int dl   = (lane >> 2) & 3;
    #pragma unroll
    for (int j = 0; j < 4; ++j) {
        int ncol_base = jt * 128 + wn * 64 + j * 16;
        int d = (ncol_base >> 2) + dl;
        float b0 = bias[0 * 128 + d];
        float b1 = bias[1 * 128 + d];
        float b2 = bias[2 * 128 + d];
        float b3 = bias[3 * 128 + d];
        #pragma unroll
        for (int i = 0; i < 4; ++i) {
            f4_t A = acc[i][j];
            float s0 = pickv(A, g);
            float s1 = pickv(A, g ^ 1);
            float s2 = pickv(A, g ^ 2);
            float s3 = pickv(A, g ^ 3);
            float u0 = s0;
            float u1 = __shfl_xor(s1, 1);
            float u2 = __shfl_xor(s2, 2);
            float u3 = __shfl_xor(s3, 3);
            float p0 = pick4(u0, u1, u2, u3, g) + b0;
            float p1 = pick4(u0, u1, u2, u3, g ^ 1) + b1;
            float p2 = pick4(u0, u1, u2, u3, g ^ 2) + b2;
            float p3 = pick4(u0, u1, u2, u3, g ^ 3) + b3;
            float ig = sigm_(p0);
            float og = sigm_(p1);
            float fg = sigm_(p2);
            float cg = tanh_(p3);
            int row = mt * 128 + wm * 64 + i * 16 + qrow * 4 + g;
            size_t off = (size_t)row * H_ + d;
            float c_old = c_src[off];
            float c_new = fg * c_old + ig * cg;
            if (write_c) c_dst[off] = c_new;
            h_dst[off] = og * tanh_(c_new);
        }
    }
}

extern "C" void kernel_launch(void* const* d_in, const int* in_sizes, int n_in,
                              void* d_out, int out_size, void* d_ws, size_t ws_size,
                              hipStream_t stream) {
    const float* node_hidden = (const float*)d_in[0];
    const float* cell        = (const float*)d_in[1];
    const float* w_in        = (const float*)d_in[2];
    const float* w_out       = (const float*)d_in[3];
    const float* u_in        = (const float*)d_in[4];
    const float* u_out       = (const float*)d_in[5];
    const float* bias        = (const float*)d_in[6];
    const float* in_mask     = (const float*)d_in[7];
    const float* out_mask    = (const float*)d_in[8];
    const int*   in_idx      = (const int*)d_in[9];
    const int*   out_idx     = (const int*)d_in[10];
    float* out = (float*)d_out;

    char* p = (char*)d_ws;
    unsigned short* wp_hi = (unsigned short*)p; p += (size_t)NTILES * NCHUNK * 512 * 2;      // 384 KB
    unsigned short* wp_lo = (unsigned short*)p; p += (size_t)NTILES * NCHUNK * 512 * 2;
    unsigned short* A_hi  = (unsigned short*)p; p += (size_t)(M_/16) * NCHUNK * 512 * 2;     // 12 MB
    unsigned short* A_lo  = (unsigned short*)p; p += (size_t)(M_/16) * NCHUNK * 512 * 2;
    float* h_buf = (float*)p;                   p += (size_t)M_ * H_ * 4;                    // 8 MB
    // total ~33 MB; layer-0 c lives in d_out (overwritten by layer-1 h)

    // layer 0 agg + W prep in one dispatch
    agg0_prep_kernel<<<AGG_BLOCKS + PREP_BLOCKS, 256, 0, stream>>>(
        node_hidden, in_idx, in_mask, out_idx, out_mask, A_hi, A_lo,
        w_in, w_out, u_in, u_out, wp_hi, wp_lo);
    gemm_gates<<<GEMM_BLOCKS, 256, 0, stream>>>(
        A_hi, A_lo, wp_hi, wp_lo, bias, cell, out, h_buf, 1);

    // layer 1
    agg_kernel<<<AGG_BLOCKS, 256, 0, stream>>>(h_buf, in_idx, in_mask,
                                               out_idx, out_mask, A_hi, A_lo);
    gemm_gates<<<GEMM_BLOCKS, 256, 0, stream>>>(
        A_hi, A_lo, wp_hi, wp_lo, bias, out, out, out, 0);
}

// Round 12
// 186.833 us; speedup vs baseline: 2.3311x; 1.0124x over previous
//
#include <hip/hip_runtime.h>
#include <math.h>

#define B_ 8
#define N_ 2000
#define H_ 128
#define K_ 32
#define M_ (B_*N_)     // 16000
#define KTOT 384       // [in_agg(128) | out_agg(128) | h(128)]
#define NC 512         // cols j = d*4 + g
#define NTILES 32      // NC/16
#define NCHUNK 12      // KTOT/32
#define AGG_BLOCKS (M_ / 8)           // 2000
#define PREP_BLOCKS (NTILES * NCHUNK) // 384
#define GEMM_BLOCKS 1024              // 8 XCDs x <=128 tile-slots (128x64 tiles)

typedef __attribute__((ext_vector_type(8))) short s8_t;
typedef __attribute__((ext_vector_type(4))) float f4_t;

__device__ __forceinline__ unsigned short f2bf(float x) {
    union { float f; unsigned u; } v; v.f = x;
    unsigned r = v.u + 0x7fff + ((v.u >> 16) & 1);   // RN-even
    return (unsigned short)(r >> 16);
}
__device__ __forceinline__ float bf2f(unsigned short b) {
    union { unsigned u; float f; } v; v.u = (unsigned)b << 16; return v.f;
}
__device__ __forceinline__ float sigm_(float x) { return 1.f / (1.f + __expf(-x)); }
__device__ __forceinline__ float tanh_(float x) { return 2.f / (1.f + __expf(-2.f * x)) - 1.f; }

__device__ __forceinline__ float pickv(f4_t A, int m) {
    float ab = (m & 1) ? A.y : A.x;
    float cd = (m & 1) ? A.w : A.z;
    return (m & 2) ? cd : ab;
}
__device__ __forceinline__ float pick4(float u0, float u1, float u2, float u3, int m) {
    float ab = (m & 1) ? u1 : u0;
    float cd = (m & 1) ? u3 : u2;
    return (m & 2) ? cd : ab;
}

__device__ __forceinline__ void split4(const float* f, ushort4& hi, ushort4& lo) {
    unsigned short h0 = f2bf(f[0]), h1 = f2bf(f[1]), h2 = f2bf(f[2]), h3 = f2bf(f[3]);
    hi = make_ushort4(h0, h1, h2, h3);
    lo = make_ushort4(f2bf(f[0] - bf2f(h0)), f2bf(f[1] - bf2f(h1)),
                      f2bf(f[2] - bf2f(h2)), f2bf(f[3] - bf2f(h3)));
}

// async global->LDS, 16 B per lane; LDS dest = wave-uniform base + lane*16
__device__ __forceinline__ void gload_lds(const unsigned short* g, short* l) {
    __builtin_amdgcn_global_load_lds(
        (const __attribute__((address_space(1))) unsigned*)g,
        (__attribute__((address_space(3))) unsigned*)l, 16, 0, 0);
}

// W prep: element t (0..511) of prep-block pb = (ntile*NCHUNK + chunk).
__device__ __forceinline__ void prep_elem(int pb, int t,
                                          const float* __restrict__ w_in,
                                          const float* __restrict__ w_out,
                                          const float* __restrict__ u_in,
                                          const float* __restrict__ u_out,
                                          unsigned short* __restrict__ wp_hi,
                                          unsigned short* __restrict__ wp_lo) {
    int ntile = pb / NCHUNK, chunk = pb % NCHUNK;
    int lane = t >> 3, e = t & 7;
    int col = ntile * 16 + (lane & 15);
    int k = chunk * 32 + (lane >> 4) * 8 + e;
    int d = col >> 2, g = col & 3;
    float v;
    if (k < 128) {
        v = w_in[(g * 128 + k) * 128 + d];
    } else if (k < 256) {
        v = w_out[(g * 128 + (k - 128)) * 128 + d];
    } else {
        int kk = k - 256;
        v = u_in[(g * 128 + kk) * 128 + d] + u_out[(g * 128 + kk) * 128 + d];
    }
    unsigned short hs = f2bf(v);
    wp_hi[(size_t)pb * 512 + t] = hs;
    wp_lo[(size_t)pb * 512 + t] = f2bf(v - bf2f(hs));
}

// Gather + masked aggregate + u-term pack for agg-unit a (rows 8a..8a+7);
// output split-bf16 in MFMA A-fragment layout (verified R4-R11).
__device__ __forceinline__ void agg_body(int a, int tid,
                                         const float* __restrict__ h,
                                         const int* __restrict__ in_idx,
                                         const float* __restrict__ in_mask,
                                         const int* __restrict__ out_idx,
                                         const float* __restrict__ out_mask,
                                         unsigned short* __restrict__ A_hi,
                                         unsigned short* __restrict__ A_lo,
                                         int (*s_idx)[64], float (*s_msk)[64]) {
    int r = tid >> 5;            // 0..7 row within unit
    int p = tid & 31;            // dim group: dims p*4 .. p*4+3
    int row = a * 8 + r;
    int b = row / N_;
    const float* hb = h + (size_t)b * N_ * H_;

    for (int e = tid; e < 512; e += 256) {
        int r2 = e >> 6, q = e & 63;
        int ridx = a * 8 + r2;
        if (q < 32) {
            s_idx[r2][q] = in_idx[ridx * K_ + q];
            s_msk[r2][q] = in_mask[ridx * K_ + q];
        } else {
            s_idx[r2][q] = out_idx[ridx * K_ + (q - 32)];
            s_msk[r2][q] = out_mask[ridx * K_ + (q - 32)];
        }
    }
    __syncthreads();

    int d0 = p * 4;
    float ai[4] = {0.f, 0.f, 0.f, 0.f};
    float ao[4] = {0.f, 0.f, 0.f, 0.f};
    #pragma unroll 16
    for (int k = 0; k < K_; ++k) {
        int   i1 = s_idx[r][k];
        float m1 = s_msk[r][k];
        int   i2 = s_idx[r][32 + k];
        float m2 = s_msk[r][32 + k];
        float4 v1 = *(const float4*)(hb + (size_t)i1 * H_ + d0);
        float4 v2 = *(const float4*)(hb + (size_t)i2 * H_ + d0);
        ai[0] += m1 * v1.x; ai[1] += m1 * v1.y; ai[2] += m1 * v1.z; ai[3] += m1 * v1.w;
        ao[0] += m2 * v2.x; ao[1] += m2 * v2.y; ao[2] += m2 * v2.z; ao[3] += m2 * v2.w;
    }
    float4 hv4 = *(const float4*)(h + (size_t)row * H_ + d0);
    float hh[4] = {hv4.x, hv4.y, hv4.z, hv4.w};

    int mtile = row >> 4;
    int kg = (p >> 1) & 3;
    int e0 = (p & 1) * 4;
    int lane = (row & 15) + 16 * kg;
    size_t bi = ((size_t)(mtile * NCHUNK +     (p >> 3)) * 64 + lane) * 8 + e0;
    size_t bo = ((size_t)(mtile * NCHUNK + 4 + (p >> 3)) * 64 + lane) * 8 + e0;
    size_t bh = ((size_t)(mtile * NCHUNK + 8 + (p >> 3)) * 64 + lane) * 8 + e0;

    ushort4 hi, lo;
    split4(ai, hi, lo); *(ushort4*)(A_hi + bi) = hi; *(ushort4*)(A_lo + bi) = lo;
    split4(ao, hi, lo); *(ushort4*)(A_hi + bo) = hi; *(ushort4*)(A_lo + bo) = lo;
    split4(hh, hi, lo); *(ushort4*)(A_hi + bh) = hi; *(ushort4*)(A_lo + bh) = lo;
}

// Layer-0 combined dispatch: blocks [0,2000) = agg on node_hidden,
// blocks [2000, 2384) = W prep.
__global__ __launch_bounds__(256)
void agg0_prep_kernel(const float* __restrict__ h,
                      const int* __restrict__ in_idx,
                      const float* __restrict__ in_mask,
                      const int* __restrict__ out_idx,
                      const float* __restrict__ out_mask,
                      unsigned short* __restrict__ A_hi,
                      unsigned short* __restrict__ A_lo,
                      const float* __restrict__ w_in,
                      const float* __restrict__ w_out,
                      const float* __restrict__ u_in,
                      const float* __restrict__ u_out,
                      unsigned short* __restrict__ wp_hi,
                      unsigned short* __restrict__ wp_lo) {
    __shared__ int   s_idx[8][64];
    __shared__ float s_msk[8][64];
    int tid = threadIdx.x;
    if (blockIdx.x < AGG_BLOCKS) {
        int bid = (blockIdx.x & 7) * 250 + (blockIdx.x >> 3);  // XCD-affinity swizzle
        agg_body(bid, tid, h, in_idx, in_mask, out_idx, out_mask,
                 A_hi, A_lo, s_idx, s_msk);
    } else {
        int pb = blockIdx.x - AGG_BLOCKS;
        prep_elem(pb, tid,       w_in, w_out, u_in, u_out, wp_hi, wp_lo);
        prep_elem(pb, tid + 256, w_in, w_out, u_in, u_out, wp_hi, wp_lo);
    }
}

// Layer-1 agg (h = h_buf)
__global__ __launch_bounds__(256)
void agg_kernel(const float* __restrict__ h,
                const int* __restrict__ in_idx,
                const float* __restrict__ in_mask,
                const int* __restrict__ out_idx,
                const float* __restrict__ out_mask,
                unsigned short* __restrict__ A_hi,
                unsigned short* __restrict__ A_lo) {
    __shared__ int   s_idx[8][64];
    __shared__ float s_msk[8][64];
    int bid = (blockIdx.x & 7) * 250 + (blockIdx.x >> 3);
    agg_body(bid, threadIdx.x, h, in_idx, in_mask, out_idx, out_mask,
             A_hi, A_lo, s_idx, s_msk);
}

// gemm v4: 128x64 block tile (8 mtiles x 4 ntiles), 1024 blocks -> 4/CU
// occupancy (vs 2/CU at 128x128) to hide the per-chunk barrier drain via
// co-resident blocks. XCD-affine: tiles of batch x run on XCD x. Per chunk
// stages 24 KB: slots 0..7 A_hi, 8..15 A_lo, 16..19 W_hi, 20..23 W_lo.
__global__ __launch_bounds__(256)
void gemm_gates(const unsigned short* __restrict__ A_hi,
                const unsigned short* __restrict__ A_lo,
                const unsigned short* __restrict__ wp_hi,
                const unsigned short* __restrict__ wp_lo,
                const float* __restrict__ bias,
                const float* __restrict__ c_src,
                float* __restrict__ c_dst,
                float* __restrict__ h_dst,
                int write_c) {
    __shared__ short sL[24 * 512];   // 24 KB
    int l = blockIdx.x;
    int x = l & 7;                   // XCD (round-robin dispatch)
    int s_slot = l >> 3;             // 0..127
    int mt_lo  = x ? ((2000 * x + 63) >> 7) : 0;
    int mt_nxt = (2000 * (x + 1) + 63) >> 7;         // x=7 -> 125
    int cnt = (mt_nxt - mt_lo) * 8;                  // <=128
    if (s_slot >= cnt) return;
    int mt = mt_lo + (s_slot >> 3);                  // 0..124 (128-row tile)
    int jt = s_slot & 7;                             // 0..7  (64-col tile)

    int tid  = threadIdx.x;
    int lane = tid & 63;
    int w    = tid >> 6;         // 0..3
    int wm   = w & 1;            // 64-row half
    int wn   = w >> 1;           // 32-col half
    int mtile0 = mt * 8;
    int ntile0 = jt * 4;

    // staging: wave w owns slots {w, w+4, ..., w+20} (6 each)
    const unsigned short* gp[6];
    short* lp[6];
    #pragma unroll
    for (int i = 0; i < 6; ++i) {
        int s = i * 4 + w;
        const unsigned short* src;
        if (s < 8)       src = A_hi  + ((size_t)((mtile0 + s)      * NCHUNK) * 64 + lane) * 8;
        else if (s < 16) src = A_lo  + ((size_t)((mtile0 + s - 8)  * NCHUNK) * 64 + lane) * 8;
        else if (s < 20) src = wp_hi + ((size_t)((ntile0 + s - 16) * NCHUNK) * 64 + lane) * 8;
        else             src = wp_lo + ((size_t)((ntile0 + s - 20) * NCHUNK) * 64 + lane) * 8;
        gp[i] = src;
        lp[i] = &sL[s * 512];    // wave-uniform base; HW adds lane*16 B
    }

    f4_t zero = {0.f, 0.f, 0.f, 0.f};
    f4_t acc[4][2];
    #pragma unroll
    for (int i = 0; i < 4; ++i)
        #pragma unroll
        for (int j = 0; j < 2; ++j) acc[i][j] = zero;

    #pragma unroll 1
    for (int c = 0; c < NCHUNK; ++c) {
        if (c > 0) __syncthreads();
        #pragma unroll
        for (int i = 0; i < 6; ++i) {
            gload_lds(gp[i], lp[i]);
            gp[i] += 512;
        }
        __syncthreads();

        s8_t a_hi[4], a_lo[4], b_hi[2], b_lo[2];
        #pragma unroll
        for (int i = 0; i < 4; ++i) {
            a_hi[i] = *(const s8_t*)&sL[(wm * 4 + i) * 512 + lane * 8];
            a_lo[i] = *(const s8_t*)&sL[(8 + wm * 4 + i) * 512 + lane * 8];
        }
        #pragma unroll
        for (int j = 0; j < 2; ++j) {
            b_hi[j] = *(const s8_t*)&sL[(16 + wn * 2 + j) * 512 + lane * 8];
            b_lo[j] = *(const s8_t*)&sL[(20 + wn * 2 + j) * 512 + lane * 8];
        }
        #pragma unroll
        for (int i = 0; i < 4; ++i)
            #pragma unroll
            for (int j = 0; j < 2; ++j) {
                acc[i][j] = __builtin_amdgcn_mfma_f32_16x16x32_bf16(a_hi[i], b_hi[j], acc[i][j], 0, 0, 0);
                acc[i][j] = __builtin_amdgcn_mfma_f32_16x16x32_bf16(a_hi[i], b_lo[j], acc[i][j], 0, 0, 0);
                acc[i][j] = __builtin_amdgcn_mfma_f32_16x16x32_bf16(a_lo[i], b_hi[j], acc[i][j], 0, 0, 0);
            }
    }

    // ---- epilogue: gate exchange + cell/h update (verified R2-R11) ----
    int g    = lane & 3;
    int qrow = lane >> 4;
    int dl   = (lane >> 2) & 3;
    #pragma unroll
    for (int j = 0; j < 2; ++j) {
        int ncol_base = jt * 64 + wn * 32 + j * 16;
        int d = (ncol_base >> 2) + dl;
        float b0 = bias[0 * 128 + d];
        float b1 = bias[1 * 128 + d];
        float b2 = bias[2 * 128 + d];
        float b3 = bias[3 * 128 + d];
        #pragma unroll
        for (int i = 0; i < 4; ++i) {
            f4_t A = acc[i][j];
            float s0 = pickv(A, g);
            float s1 = pickv(A, g ^ 1);
            float s2 = pickv(A, g ^ 2);
            float s3 = pickv(A, g ^ 3);
            float u0 = s0;
            float u1 = __shfl_xor(s1, 1);
            float u2 = __shfl_xor(s2, 2);
            float u3 = __shfl_xor(s3, 3);
            float p0 = pick4(u0, u1, u2, u3, g) + b0;
            float p1 = pick4(u0, u1, u2, u3, g ^ 1) + b1;
            float p2 = pick4(u0, u1, u2, u3, g ^ 2) + b2;
            float p3 = pick4(u0, u1, u2, u3, g ^ 3) + b3;
            float ig = sigm_(p0);
            float og = sigm_(p1);
            float fg = sigm_(p2);
            float cg = tanh_(p3);
            int row = mt * 128 + wm * 64 + i * 16 + qrow * 4 + g;
            size_t off = (size_t)row * H_ + d;
            float c_old = c_src[off];
            float c_new = fg * c_old + ig * cg;
            if (write_c) c_dst[off] = c_new;
            h_dst[off] = og * tanh_(c_new);
        }
    }
}

extern "C" void kernel_launch(void* const* d_in, const int* in_sizes, int n_in,
                              void* d_out, int out_size, void* d_ws, size_t ws_size,
                              hipStream_t stream) {
    const float* node_hidden = (const float*)d_in[0];
    const float* cell        = (const float*)d_in[1];
    const float* w_in        = (const float*)d_in[2];
    const float* w_out       = (const float*)d_in[3];
    const float* u_in        = (const float*)d_in[4];
    const float* u_out       = (const float*)d_in[5];
    const float* bias        = (const float*)d_in[6];
    const float* in_mask     = (const float*)d_in[7];
    const float* out_mask    = (const float*)d_in[8];
    const int*   in_idx      = (const int*)d_in[9];
    const int*   out_idx     = (const int*)d_in[10];
    float* out = (float*)d_out;

    char* p = (char*)d_ws;
    unsigned short* wp_hi = (unsigned short*)p; p += (size_t)NTILES * NCHUNK * 512 * 2;      // 384 KB
    unsigned short* wp_lo = (unsigned short*)p; p += (size_t)NTILES * NCHUNK * 512 * 2;
    unsigned short* A_hi  = (unsigned short*)p; p += (size_t)(M_/16) * NCHUNK * 512 * 2;     // 12 MB
    unsigned short* A_lo  = (unsigned short*)p; p += (size_t)(M_/16) * NCHUNK * 512 * 2;
    float* h_buf = (float*)p;                   p += (size_t)M_ * H_ * 4;                    // 8 MB
    // total ~33 MB; layer-0 c lives in d_out (overwritten by layer-1 h)

    // layer 0 agg + W prep in one dispatch
    agg0_prep_kernel<<<AGG_BLOCKS + PREP_BLOCKS, 256, 0, stream>>>(
        node_hidden, in_idx, in_mask, out_idx, out_mask, A_hi, A_lo,
        w_in, w_out, u_in, u_out, wp_hi, wp_lo);
    gemm_gates<<<GEMM_BLOCKS, 256, 0, stream>>>(
        A_hi, A_lo, wp_hi, wp_lo, bias, cell, out, h_buf, 1);

    // layer 1
    agg_kernel<<<AGG_BLOCKS, 256, 0, stream>>>(h_buf, in_idx, in_mask,
                                               out_idx, out_mask, A_hi, A_lo);
    gemm_gates<<<GEMM_BLOCKS, 256, 0, stream>>>(
        A_hi, A_lo, wp_hi, wp_lo, bias, out, out, out, 0);
}